// Round 8
// baseline (236.060 us; speedup 1.0000x reference)
//
#include <hip/hip_runtime.h>
#include <hip/hip_bf16.h>

#define HDIM 128
#define PGB 160   // persistent proj blocks per gene section
#define PDB 32    // persistent proj blocks for disease section
#define ENB 512   // persistent edge blocks per relation

typedef __attribute__((ext_vector_type(8))) short short8;
typedef __attribute__((ext_vector_type(4))) float floatx4;

__device__ __forceinline__ float bf2f(unsigned short u) {
    return __uint_as_float(((unsigned)u) << 16);
}
__device__ __forceinline__ unsigned short f2b(float f) {
    __hip_bfloat16 h = __float2bfloat16(f);
    return __builtin_bit_cast(unsigned short, h);
}
__device__ __forceinline__ float ldv(const void* p, size_t i, int flag) {
    return flag ? bf2f(((const unsigned short*)p)[i]) : ((const float*)p)[i];
}
__device__ __forceinline__ short8 pack8(float4 a, float4 b) {
    short8 r;
    r[0] = (short)f2b(a.x); r[1] = (short)f2b(a.y);
    r[2] = (short)f2b(a.z); r[3] = (short)f2b(a.w);
    r[4] = (short)f2b(b.x); r[5] = (short)f2b(b.y);
    r[6] = (short)f2b(b.z); r[7] = (short)f2b(b.w);
    return r;
}

// ---------------------------------------------------------------------------
// Block-local dtype detect (same result in every block). flag=1 -> bf16,
// 0 -> f32 (low halves of f32 are ~uniform u16 -> ~58% plausible exponents).
// ---------------------------------------------------------------------------
__device__ __forceinline__ int local_detect(const unsigned short* zbits) {
    __shared__ int red[256];
    int tid = threadIdx.x;
    int cnt = 0;
    for (int i = tid; i < 4096; i += 256) {
        int ex = (zbits[i] >> 7) & 0xFF;
        if (ex >= 100 && ex <= 140) cnt++;
    }
    red[tid] = cnt;
    __syncthreads();
    for (int s = 128; s > 0; s >>= 1) {
        if (tid < s) red[tid] += red[tid + s];
        __syncthreads();
    }
    return (red[0] >= 3686) ? 1 : 0;
}

// ---------------------------------------------------------------------------
// prep: blocks 0-31 build XOR-swizzled transposed 128x128 bf16 W images
// (swizzle keeps proj's ds_read_b128 conflict-free; measured 0 conflicts):
//   img[im][n*128 + ((k>>3)^(n&15))*8 + (k&7)] = w1[(part*128+k)*128 + n]
// im: 0=gd_top 1=gd_bot 2=gg_top 3=gg_bot.  Block 32: params to f32 + flag:
// [0:128)=b1_gd [128:256)=w2_gd [256:384)=b1_gg [384:512)=w2_gg
// [512]=b2_gd [513]=b2_gg  [768:896)=zeros (null-bias region)
// ---------------------------------------------------------------------------
__global__ __launch_bounds__(256) void prep_kernel(
    const unsigned short* __restrict__ zbits,
    const void* __restrict__ w1_gd, const void* __restrict__ w1_gg,
    const void* __restrict__ b1_gd, const void* __restrict__ w2_gd,
    const void* __restrict__ b2_gd, const void* __restrict__ b1_gg,
    const void* __restrict__ w2_gg, const void* __restrict__ b2_gg,
    unsigned short* __restrict__ img, float* __restrict__ params,
    int* __restrict__ flagout)
{
    int flag = local_detect(zbits);
    int b = blockIdx.x;
    int tid = threadIdx.x;
    if (b < 32) {
        int im   = b >> 3;          // image id
        int sub  = b & 7;           // 16 k-rows per sub-block
        const void* w1 = (im < 2) ? w1_gd : w1_gg;
        int part = im & 1;
        unsigned short* out = img + im * 16384;
        int n = tid & 127;
#pragma unroll
        for (int it = 0; it < 8; ++it) {
            int k = sub * 16 + it * 2 + (tid >> 7);
            unsigned short v = flag
                ? ((const unsigned short*)w1)[(size_t)(part * 128 + k) * 128 + n]
                : f2b(((const float*)w1)[(size_t)(part * 128 + k) * 128 + n]);
            out[n * 128 + (((k >> 3) ^ (n & 15)) << 3) + (k & 7)] = v;
        }
    } else {
        if (tid < 128) {
            params[tid]       = ldv(b1_gd, tid, flag);
            params[256 + tid] = ldv(b1_gg, tid, flag);
            params[768 + tid] = 0.f;               // null-bias region
        } else {
            params[tid]       = ldv(w2_gd, tid - 128, flag);
            params[256 + tid] = ldv(w2_gg, tid - 128, flag);
        }
        if (tid == 0) {
            params[512] = ldv(b2_gd, 0, flag);
            params[513] = ldv(b2_gg, 0, flag);
            *flagout = flag;
        }
    }
}

// ---------------------------------------------------------------------------
// proj raw Z-tile load (issue only; no use). 2 rows x 128 cols per lane-pair
// layout; BF16: 8 uint4/lane, F32: 16 uint4/lane.
// ---------------------------------------------------------------------------
template<bool BF16>
__device__ __forceinline__ void load_raw(const void* __restrict__ Z, int t, int M,
                                         int wave, int nl, int quad, uint4* raw)
{
    int row0 = t * 128 + wave * 32 + nl;
    int row1 = row0 + 16;
    int r0 = row0 < M ? row0 : M - 1;
    int r1 = row1 < M ? row1 : M - 1;
    if (BF16) {
        const uint4* z0 = (const uint4*)Z + (size_t)r0 * 16;
        const uint4* z1 = (const uint4*)Z + (size_t)r1 * 16;
#pragma unroll
        for (int kc = 0; kc < 4; ++kc) {
            raw[kc]     = z0[kc * 4 + quad];
            raw[4 + kc] = z1[kc * 4 + quad];
        }
    } else {
        const uint4* z0 = (const uint4*)Z + (size_t)r0 * 32;
        const uint4* z1 = (const uint4*)Z + (size_t)r1 * 32;
#pragma unroll
        for (int kc = 0; kc < 4; ++kc) {
            int o = kc * 8 + quad * 2;
            raw[2 * kc]         = z0[o];
            raw[2 * kc + 1]     = z0[o + 1];
            raw[8 + 2 * kc]     = z1[o];
            raw[8 + 2 * kc + 1] = z1[o + 1];
        }
    }
}

template<bool BF16>
__device__ __forceinline__ void to_frags(const uint4* raw, short8 zf[2][4])
{
#pragma unroll
    for (int kc = 0; kc < 4; ++kc) {
        if (BF16) {
            zf[0][kc] = __builtin_bit_cast(short8, raw[kc]);
            zf[1][kc] = __builtin_bit_cast(short8, raw[4 + kc]);
        } else {
            zf[0][kc] = pack8(__builtin_bit_cast(float4, raw[2 * kc]),
                              __builtin_bit_cast(float4, raw[2 * kc + 1]));
            zf[1][kc] = pack8(__builtin_bit_cast(float4, raw[8 + 2 * kc]),
                              __builtin_bit_cast(float4, raw[8 + 2 * kc + 1]));
        }
    }
}

// ---------------------------------------------------------------------------
// proj tile loop: W resident in LDS (read-only after one barrier), no
// barriers inside; next tile's Z loads issued before current tile's MFMAs
// (register double-buffer) so Z latency hides behind MFMA + stores.
// W = MFMA A-operand (m = out col), Z = B-operand (n = out row); lane's 4
// accum regs = 4 consecutive out cols of one row -> ushort4 stores.
// ---------------------------------------------------------------------------
template<bool BF16>
__device__ void proj_loop(const void* __restrict__ Z,
                          unsigned short* __restrict__ Out,
                          const float* __restrict__ bias,
                          const uint4* sW, int M, int ntiles,
                          int t0, int nb, int wave, int nl, int quad)
{
    constexpr int NR = BF16 ? 8 : 16;
    uint4 raw[NR];
    int t = t0;
    if (t < ntiles) load_raw<BF16>(Z, t, M, wave, nl, quad, raw);
    while (t < ntiles) {
        short8 zf[2][4];
        to_frags<BF16>(raw, zf);             // waits on raw loads

        int tn = t + nb;
        if (tn < ntiles) load_raw<BF16>(Z, tn, M, wave, nl, quad, raw);  // prefetch

        floatx4 acc[2][8];
#pragma unroll
        for (int rt = 0; rt < 2; ++rt)
#pragma unroll
            for (int nt = 0; nt < 8; ++nt)
                acc[rt][nt] = (floatx4){0.f, 0.f, 0.f, 0.f};

#pragma unroll
        for (int kc = 0; kc < 4; ++kc) {
            int p = (kc * 4 + quad) ^ nl;    // undo XOR swizzle
#pragma unroll
            for (int nt = 0; nt < 8; ++nt) {
                short8 wf = __builtin_bit_cast(short8, sW[(nt * 16 + nl) * 16 + p]);
                acc[0][nt] = __builtin_amdgcn_mfma_f32_16x16x32_bf16(wf, zf[0][kc], acc[0][nt], 0, 0, 0);
                acc[1][nt] = __builtin_amdgcn_mfma_f32_16x16x32_bf16(wf, zf[1][kc], acc[1][nt], 0, 0, 0);
            }
        }

        int row0 = t * 128 + wave * 32 + nl;
#pragma unroll
        for (int rt = 0; rt < 2; ++rt) {
            int row = row0 + rt * 16;
            if (row < M) {
#pragma unroll
                for (int nt = 0; nt < 8; ++nt) {
                    float4 bv = *(const float4*)(bias + nt * 16 + quad * 4);
                    ushort4 v;
                    v.x = f2b(acc[rt][nt][0] + bv.x);
                    v.y = f2b(acc[rt][nt][1] + bv.y);
                    v.z = f2b(acc[rt][nt][2] + bv.z);
                    v.w = f2b(acc[rt][nt][3] + bv.w);
                    *(ushort4*)(Out + (size_t)row * HDIM + nt * 16 + quad * 4) = v;
                }
            }
        }
        t = tn;
    }
}

// ---------------------------------------------------------------------------
// proj: persistent blocks. Sections: [0,PGB) img0->A_gd(+b1_gd) |
// [PGB,2PGB) img2->A_gg(+b1_gg) | [2PGB,3PGB) img3->B_gg |
// [3PGB,3PGB+PDB) img1->B_gd (disease). W staged once, one barrier total.
// ---------------------------------------------------------------------------
__global__ __launch_bounds__(256) void proj_kernel(
    const void* __restrict__ Zg, const void* __restrict__ Zd,
    const uint4* __restrict__ img, const float* __restrict__ params,
    unsigned short* __restrict__ A_gd, unsigned short* __restrict__ B_gd,
    unsigned short* __restrict__ A_gg, unsigned short* __restrict__ B_gg,
    int NG, int ND, const int* __restrict__ flagp)
{
    __shared__ uint4 sW[2048];  // 32 KB
    int id = blockIdx.x;
    const void* Z; int M; const uint4* W; unsigned short* Out; const float* bias;
    int lblk, nb;
    if (id < PGB)            { Z = Zg; M = NG; W = img;        Out = A_gd; bias = params;       lblk = id;           nb = PGB; }
    else if (id < 2 * PGB)   { Z = Zg; M = NG; W = img + 4096; Out = A_gg; bias = params + 256; lblk = id - PGB;     nb = PGB; }
    else if (id < 3 * PGB)   { Z = Zg; M = NG; W = img + 6144; Out = B_gg; bias = params + 768; lblk = id - 2 * PGB; nb = PGB; }
    else                     { Z = Zd; M = ND; W = img + 2048; Out = B_gd; bias = params + 768; lblk = id - 3 * PGB; nb = PDB; }

    int tid  = threadIdx.x;
    int lane = tid & 63;
    int wave = tid >> 6;
    int nl   = lane & 15;
    int quad = lane >> 4;

#pragma unroll
    for (int i = 0; i < 8; ++i) sW[tid + i * 256] = W[tid + i * 256];
    __syncthreads();

    int ntiles = (M + 127) >> 7;
    if (*flagp) proj_loop<true >(Z, Out, bias, sW, M, ntiles, lblk, nb, wave, nl, quad);
    else        proj_loop<false>(Z, Out, bias, sW, M, ntiles, lblk, nb, wave, nl, quad);
}

// ---------------------------------------------------------------------------
// edge: persistent, 8 lanes/edge, 4 edges/group, next-iter idx prefetch.
// out[e] = relu(A[src]+B[dst]).w2 + b2  (b1 pre-folded into A).
// rel block-uniform -> w2/b2 scalar.
// ---------------------------------------------------------------------------
__global__ __launch_bounds__(256) void edge_kernel(
    const int* __restrict__ edges_gd, const int* __restrict__ edges_gg,
    const unsigned short* __restrict__ A_gd, const unsigned short* __restrict__ B_gd,
    const unsigned short* __restrict__ A_gg, const unsigned short* __restrict__ B_gg,
    const float* __restrict__ params,
    void* __restrict__ out, int E, const int* __restrict__ flagp)
{
    int rel = ((int)blockIdx.x >= ENB) ? 1 : 0;
    int blk = blockIdx.x - rel * ENB;
    const int* edges = rel ? edges_gg : edges_gd;
    const unsigned short* A = rel ? A_gg : A_gd;
    const unsigned short* B = rel ? B_gg : B_gd;
    const float* w2 = params + 128 + rel * 256;   // block-uniform
    float b2 = params[512 + rel];
    int flag = *flagp;

    int tid  = threadIdx.x;
    int lane = tid & 63;
    int wave = tid >> 6;
    int nl   = lane & 7;    // lane within edge-group
    int grp  = lane >> 3;   // 8 groups per wave

    float w2f[16];
#pragma unroll
    for (int i = 0; i < 4; ++i) {
        float4 t = *(const float4*)(w2 + nl * 16 + i * 4);
        w2f[i * 4 + 0] = t.x; w2f[i * 4 + 1] = t.y;
        w2f[i * 4 + 2] = t.z; w2f[i * 4 + 3] = t.w;
    }

    int ngroups = (E + 3) >> 2;
    int ecap = (E - 4) & ~3;          // aligned max int4 base
    int stride = ENB * 32;            // groups per grid pass
    int g = blk * 32 + wave * 8 + grp;
    size_t obase = (size_t)rel * E;

    int4 sp, dp;
    if (g < ngroups) {
        int ec = 4 * g; if (ec > ecap) ec = ecap;
        sp = *(const int4*)(edges + ec);
        dp = *(const int4*)(edges + E + ec);
    }
    while (g < ngroups) {
        int e0 = 4 * g;
        int ec = e0 > ecap ? ecap : e0;
        int s0 = sp.x, s1 = sp.y, s2 = sp.z, s3 = sp.w;
        int d0 = dp.x, d1 = dp.y, d2 = dp.z, d3 = dp.w;
        if (e0 != ec) {   // rare tail fixup (only when E%4 != 0)
            s0 = (e0 + 0 < E) ? edges[e0 + 0] : s0;  d0 = (e0 + 0 < E) ? edges[E + e0 + 0] : d0;
            s1 = (e0 + 1 < E) ? edges[e0 + 1] : s1;  d1 = (e0 + 1 < E) ? edges[E + e0 + 1] : d1;
            s2 = (e0 + 2 < E) ? edges[e0 + 2] : s2;  d2 = (e0 + 2 < E) ? edges[E + e0 + 2] : d2;
            s3 = (e0 + 3 < E) ? edges[e0 + 3] : s3;  d3 = (e0 + 3 < E) ? edges[E + e0 + 3] : d3;
        }

        const uint4* ap0 = (const uint4*)(A + (size_t)s0 * HDIM) + nl * 2;
        const uint4* bp0 = (const uint4*)(B + (size_t)d0 * HDIM) + nl * 2;
        const uint4* ap1 = (const uint4*)(A + (size_t)s1 * HDIM) + nl * 2;
        const uint4* bp1 = (const uint4*)(B + (size_t)d1 * HDIM) + nl * 2;
        const uint4* ap2 = (const uint4*)(A + (size_t)s2 * HDIM) + nl * 2;
        const uint4* bp2 = (const uint4*)(B + (size_t)d2 * HDIM) + nl * 2;
        const uint4* ap3 = (const uint4*)(A + (size_t)s3 * HDIM) + nl * 2;
        const uint4* bp3 = (const uint4*)(B + (size_t)d3 * HDIM) + nl * 2;

        uint4 a[4][2], c[4][2];
        a[0][0] = ap0[0]; a[0][1] = ap0[1]; c[0][0] = bp0[0]; c[0][1] = bp0[1];
        a[1][0] = ap1[0]; a[1][1] = ap1[1]; c[1][0] = bp1[0]; c[1][1] = bp1[1];
        a[2][0] = ap2[0]; a[2][1] = ap2[1]; c[2][0] = bp2[0]; c[2][1] = bp2[1];
        a[3][0] = ap3[0]; a[3][1] = ap3[1]; c[3][0] = bp3[0]; c[3][1] = bp3[1];

        int gn = g + stride;
        if (gn < ngroups) {   // prefetch next indices while data is in flight
            int ecn = 4 * gn; if (ecn > ecap) ecn = ecap;
            sp = *(const int4*)(edges + ecn);
            dp = *(const int4*)(edges + E + ecn);
        }

        float acc[4] = {0.f, 0.f, 0.f, 0.f};
#pragma unroll
        for (int k = 0; k < 4; ++k) {
#pragma unroll
            for (int i = 0; i < 2; ++i) {
                const unsigned* au = (const unsigned*)&a[k][i];
                const unsigned* cu = (const unsigned*)&c[k][i];
#pragma unroll
                for (int j = 0; j < 4; ++j) {
                    int ch = i * 8 + j * 2;
                    float x0 = __uint_as_float(au[j] << 16);
                    float x1 = __uint_as_float(au[j] & 0xffff0000u);
                    float y0 = __uint_as_float(cu[j] << 16);
                    float y1 = __uint_as_float(cu[j] & 0xffff0000u);
                    acc[k] = fmaf(fmaxf(x0 + y0, 0.f), w2f[ch], acc[k]);
                    acc[k] = fmaf(fmaxf(x1 + y1, 0.f), w2f[ch + 1], acc[k]);
                }
            }
        }
#pragma unroll
        for (int k = 0; k < 4; ++k) {
            acc[k] += __shfl_xor(acc[k], 1);
            acc[k] += __shfl_xor(acc[k], 2);
            acc[k] += __shfl_xor(acc[k], 4);
        }

        if (nl == 0) {
            float r0 = acc[0] + b2, r1 = acc[1] + b2, r2 = acc[2] + b2, r3 = acc[3] + b2;
            if (e0 == ec && e0 + 3 < E) {
                if (flag) {
                    ushort4 v = {f2b(r0), f2b(r1), f2b(r2), f2b(r3)};
                    *(ushort4*)((unsigned short*)out + obase + e0) = v;
                } else {
                    float4 v = {r0, r1, r2, r3};
                    *(float4*)((float*)out + obase + e0) = v;
                }
            } else {
                float rr[4] = {r0, r1, r2, r3};
#pragma unroll
                for (int k = 0; k < 4; ++k) {
                    if (e0 + k < E) {
                        if (flag) ((unsigned short*)out)[obase + e0 + k] = f2b(rr[k]);
                        else      ((float*)out)[obase + e0 + k] = rr[k];
                    }
                }
            }
        }
        g = gn;
    }
}

// ---------------------------------------------------------------------------
// Fallback path (ws too small): detect + full per-edge MLP, one edge/block.
// ---------------------------------------------------------------------------
__global__ __launch_bounds__(256) void detect_kernel(
    const unsigned short* __restrict__ zbits, int* __restrict__ flag)
{
    int f = local_detect(zbits);
    if (threadIdx.x == 0) *flag = f;
}

__global__ __launch_bounds__(128) void naive_edge_kernel(
    const int* __restrict__ edges,
    const void* __restrict__ zsrc, const void* __restrict__ zdst,
    const void* __restrict__ w1, const void* __restrict__ b1,
    const void* __restrict__ w2, const void* __restrict__ b2,
    void* __restrict__ out, size_t eoff, int E,
    const int* __restrict__ flagp)
{
    int flag = flagp ? *flagp : 0;
    __shared__ float zs[128], zd[128], red[128];
    int e = blockIdx.x;
    int n = threadIdx.x;
    int src = edges[e], dst = edges[E + e];
    zs[n] = ldv(zsrc, (size_t)src * HDIM + n, flag);
    zd[n] = ldv(zdst, (size_t)dst * HDIM + n, flag);
    __syncthreads();
    float acc = ldv(b1, n, flag);
    for (int k = 0; k < 128; ++k) acc = fmaf(zs[k], ldv(w1, (size_t)k * HDIM + n, flag), acc);
    for (int k = 0; k < 128; ++k) acc = fmaf(zd[k], ldv(w1, (size_t)(128 + k) * HDIM + n, flag), acc);
    red[n] = fmaxf(acc, 0.f) * ldv(w2, n, flag);
    __syncthreads();
    for (int s = 64; s > 0; s >>= 1) {
        if (n < s) red[n] += red[n + s];
        __syncthreads();
    }
    if (n == 0) {
        float r = red[0] + ldv(b2, 0, flag);
        if (flag) ((unsigned short*)out)[eoff + e] = f2b(r);
        else      ((float*)out)[eoff + e] = r;
    }
}

extern "C" void kernel_launch(void* const* d_in, const int* in_sizes, int n_in,
                              void* d_out, int out_size, void* d_ws, size_t ws_size,
                              hipStream_t stream)
{
    const void* z_gene = d_in[0];
    const void* z_dis  = d_in[1];
    const int* edges_gd = (const int*)d_in[2];
    const int* edges_gg = (const int*)d_in[3];
    const void* w1_gd = d_in[4];
    const void* b1_gd = d_in[5];
    const void* w2_gd = d_in[6];
    const void* b2_gd = d_in[7];
    const void* w1_gg = d_in[8];
    const void* b1_gg = d_in[9];
    const void* w2_gg = d_in[10];
    const void* b2_gg = d_in[11];

    int NG = in_sizes[0] / HDIM;   // 100000
    int ND = in_sizes[1] / HDIM;   // 20000
    int E  = in_sizes[2] / 2;      // 500000

    // workspace layout (bytes)
    size_t off_flag   = 0;
    size_t off_params = 256;
    size_t off_img    = 256 + 4096;                     // params: 896 f32 padded
    size_t off_Agd    = off_img + 131072;
    size_t off_Bgd    = off_Agd + (size_t)NG * HDIM * 2;
    size_t off_Agg    = off_Bgd + (size_t)ND * HDIM * 2;
    size_t off_Bgg    = off_Agg + (size_t)NG * HDIM * 2;
    size_t need       = off_Bgg + (size_t)NG * HDIM * 2;

    char* ws = (char*)d_ws;

    if (ws_size < need) {
        const int* flagp = nullptr;
        if (ws_size >= 16) {
            detect_kernel<<<1, 256, 0, stream>>>((const unsigned short*)z_gene, (int*)ws);
            flagp = (const int*)ws;
        }
        naive_edge_kernel<<<E, 128, 0, stream>>>(edges_gd, z_gene, z_dis,
                                                 w1_gd, b1_gd, w2_gd, b2_gd,
                                                 d_out, 0, E, flagp);
        naive_edge_kernel<<<E, 128, 0, stream>>>(edges_gg, z_gene, z_gene,
                                                 w1_gg, b1_gg, w2_gg, b2_gg,
                                                 d_out, (size_t)E, E, flagp);
        return;
    }

    int* flag = (int*)(ws + off_flag);
    float* params = (float*)(ws + off_params);
    unsigned short* img = (unsigned short*)(ws + off_img);
    unsigned short* Agd = (unsigned short*)(ws + off_Agd);
    unsigned short* Bgd = (unsigned short*)(ws + off_Bgd);
    unsigned short* Agg = (unsigned short*)(ws + off_Agg);
    unsigned short* Bgg = (unsigned short*)(ws + off_Bgg);

    prep_kernel<<<33, 256, 0, stream>>>((const unsigned short*)z_gene,
                                        w1_gd, w1_gg, b1_gd, w2_gd, b2_gd,
                                        b1_gg, w2_gg, b2_gg, img, params, flag);

    const uint4* img4 = (const uint4*)img;
    proj_kernel<<<3 * PGB + PDB, 256, 0, stream>>>(z_gene, z_dis, img4, params,
                                                   Agd, Bgd, Agg, Bgg,
                                                   NG, ND, flag);

    edge_kernel<<<2 * ENB, 256, 0, stream>>>(edges_gd, edges_gg, Agd, Bgd, Agg, Bgg,
                                             params, d_out, E, flag);
}

// Round 9
// 227.180 us; speedup vs baseline: 1.0391x; 1.0391x over previous
//
#include <hip/hip_runtime.h>
#include <hip/hip_bf16.h>

#define HDIM 128
#define S0B 256   // persistent blocks: A_gd + A_gg (2 images in LDS)
#define S1B 128   // persistent blocks: B_gg
#define S2B 32    // persistent blocks: B_gd (disease)

typedef __attribute__((ext_vector_type(8))) short short8;
typedef __attribute__((ext_vector_type(4))) float floatx4;

__device__ __forceinline__ float bf2f(unsigned short u) {
    return __uint_as_float(((unsigned)u) << 16);
}
__device__ __forceinline__ unsigned short f2b(float f) {
    __hip_bfloat16 h = __float2bfloat16(f);
    return __builtin_bit_cast(unsigned short, h);
}
__device__ __forceinline__ float ldv(const void* p, size_t i, int flag) {
    return flag ? bf2f(((const unsigned short*)p)[i]) : ((const float*)p)[i];
}
__device__ __forceinline__ short8 pack8(float4 a, float4 b) {
    short8 r;
    r[0] = (short)f2b(a.x); r[1] = (short)f2b(a.y);
    r[2] = (short)f2b(a.z); r[3] = (short)f2b(a.w);
    r[4] = (short)f2b(b.x); r[5] = (short)f2b(b.y);
    r[6] = (short)f2b(b.z); r[7] = (short)f2b(b.w);
    return r;
}

// ---------------------------------------------------------------------------
// Block-local dtype detect (same result in every block). flag=1 -> bf16,
// 0 -> f32 (low halves of f32 are ~uniform u16 -> ~58% plausible exponents).
// ---------------------------------------------------------------------------
__device__ __forceinline__ int local_detect(const unsigned short* zbits) {
    __shared__ int red[256];
    int tid = threadIdx.x;
    int cnt = 0;
    for (int i = tid; i < 4096; i += 256) {
        int ex = (zbits[i] >> 7) & 0xFF;
        if (ex >= 100 && ex <= 140) cnt++;
    }
    red[tid] = cnt;
    __syncthreads();
    for (int s = 128; s > 0; s >>= 1) {
        if (tid < s) red[tid] += red[tid + s];
        __syncthreads();
    }
    return (red[0] >= 3686) ? 1 : 0;
}

// ---------------------------------------------------------------------------
// prep: blocks 0-31 build XOR-swizzled transposed 128x128 bf16 W images
// (swizzle keeps proj's ds_read_b128 conflict-free; measured 0 conflicts):
//   img[im][n*128 + ((k>>3)^(n&15))*8 + (k&7)] = w1[(part*128+k)*128 + n]
// im: 0=gd_top 1=gd_bot 2=gg_top 3=gg_bot.  Block 32: params to f32 + flag:
// [0:128)=b1_gd [128:256)=w2_gd [256:384)=b1_gg [384:512)=w2_gg
// [512]=b2_gd [513]=b2_gg  [768:896)=zeros (null-bias region)
// ---------------------------------------------------------------------------
__global__ __launch_bounds__(256) void prep_kernel(
    const unsigned short* __restrict__ zbits,
    const void* __restrict__ w1_gd, const void* __restrict__ w1_gg,
    const void* __restrict__ b1_gd, const void* __restrict__ w2_gd,
    const void* __restrict__ b2_gd, const void* __restrict__ b1_gg,
    const void* __restrict__ w2_gg, const void* __restrict__ b2_gg,
    unsigned short* __restrict__ img, float* __restrict__ params,
    int* __restrict__ flagout)
{
    int flag = local_detect(zbits);
    int b = blockIdx.x;
    int tid = threadIdx.x;
    if (b < 32) {
        int im   = b >> 3;          // image id
        int sub  = b & 7;           // 16 k-rows per sub-block
        const void* w1 = (im < 2) ? w1_gd : w1_gg;
        int part = im & 1;
        unsigned short* out = img + im * 16384;
        int n = tid & 127;
#pragma unroll
        for (int it = 0; it < 8; ++it) {
            int k = sub * 16 + it * 2 + (tid >> 7);
            unsigned short v = flag
                ? ((const unsigned short*)w1)[(size_t)(part * 128 + k) * 128 + n]
                : f2b(((const float*)w1)[(size_t)(part * 128 + k) * 128 + n]);
            out[n * 128 + (((k >> 3) ^ (n & 15)) << 3) + (k & 7)] = v;
        }
    } else {
        if (tid < 128) {
            params[tid]       = ldv(b1_gd, tid, flag);
            params[256 + tid] = ldv(b1_gg, tid, flag);
            params[768 + tid] = 0.f;               // null-bias region
        } else {
            params[tid]       = ldv(w2_gd, tid - 128, flag);
            params[256 + tid] = ldv(w2_gg, tid - 128, flag);
        }
        if (tid == 0) {
            params[512] = ldv(b2_gd, 0, flag);
            params[513] = ldv(b2_gg, 0, flag);
            *flagout = flag;
        }
    }
}

// ---------------------------------------------------------------------------
// proj: single Z row per lane (16 rows/wave, 64 rows/block-tile).
// raw load (issue only) + convert, register double-buffered across tiles.
// ---------------------------------------------------------------------------
template<bool BF16>
__device__ __forceinline__ void load_raw1(const void* __restrict__ Z, int row, int M,
                                          int quad, uint4* raw)
{
    int rc = row < M ? row : M - 1;
    if (BF16) {
        const uint4* z = (const uint4*)Z + (size_t)rc * 16;
#pragma unroll
        for (int kc = 0; kc < 4; ++kc) raw[kc] = z[kc * 4 + quad];
    } else {
        const uint4* z = (const uint4*)Z + (size_t)rc * 32;
#pragma unroll
        for (int kc = 0; kc < 4; ++kc) {
            int o = kc * 8 + quad * 2;
            raw[2 * kc]     = z[o];
            raw[2 * kc + 1] = z[o + 1];
        }
    }
}

template<bool BF16>
__device__ __forceinline__ void to_frags1(const uint4* raw, short8 zf[4])
{
#pragma unroll
    for (int kc = 0; kc < 4; ++kc) {
        if (BF16) {
            zf[kc] = __builtin_bit_cast(short8, raw[kc]);
        } else {
            zf[kc] = pack8(__builtin_bit_cast(float4, raw[2 * kc]),
                           __builtin_bit_cast(float4, raw[2 * kc + 1]));
        }
    }
}

// NOUT = 1 or 2 W images resident in LDS; one Z read feeds all NOUT MFMAs.
template<bool BF16, int NOUT>
__device__ void proj_loop(const void* __restrict__ Z,
                          unsigned short* __restrict__ O0,
                          unsigned short* __restrict__ O1,
                          const float* __restrict__ bias0,
                          const float* __restrict__ bias1,
                          const uint4* sW, int M, int ntiles,
                          int t0, int nb, int wave, int nl, int quad)
{
    constexpr int NR = BF16 ? 4 : 8;
    uint4 raw[NR];
    int t = t0;
    if (t < ntiles) load_raw1<BF16>(Z, t * 64 + wave * 16 + nl, M, quad, raw);
    while (t < ntiles) {
        short8 zf[4];
        to_frags1<BF16>(raw, zf);            // waits on raw loads

        int tn = t + nb;
        if (tn < ntiles) load_raw1<BF16>(Z, tn * 64 + wave * 16 + nl, M, quad, raw);

        floatx4 acc[NOUT][8];
#pragma unroll
        for (int s = 0; s < NOUT; ++s)
#pragma unroll
            for (int nt = 0; nt < 8; ++nt)
                acc[s][nt] = (floatx4){0.f, 0.f, 0.f, 0.f};

#pragma unroll
        for (int kc = 0; kc < 4; ++kc) {
            int p = (kc * 4 + quad) ^ nl;    // undo XOR swizzle
#pragma unroll
            for (int nt = 0; nt < 8; ++nt) {
                int wo = (nt * 16 + nl) * 16 + p;
                short8 wf0 = __builtin_bit_cast(short8, sW[wo]);
                acc[0][nt] = __builtin_amdgcn_mfma_f32_16x16x32_bf16(wf0, zf[kc], acc[0][nt], 0, 0, 0);
                if (NOUT == 2) {
                    short8 wf1 = __builtin_bit_cast(short8, sW[2048 + wo]);
                    acc[1][nt] = __builtin_amdgcn_mfma_f32_16x16x32_bf16(wf1, zf[kc], acc[1][nt], 0, 0, 0);
                }
            }
        }

        int row = t * 64 + wave * 16 + nl;
        if (row < M) {
#pragma unroll
            for (int s = 0; s < NOUT; ++s) {
                unsigned short* Out = s ? O1 : O0;
                const float* bias = s ? bias1 : bias0;
#pragma unroll
                for (int nt = 0; nt < 8; ++nt) {
                    float4 bv = *(const float4*)(bias + nt * 16 + quad * 4);
                    ushort4 v;
                    v.x = f2b(acc[s][nt][0] + bv.x);
                    v.y = f2b(acc[s][nt][1] + bv.y);
                    v.z = f2b(acc[s][nt][2] + bv.z);
                    v.w = f2b(acc[s][nt][3] + bv.w);
                    *(ushort4*)(Out + (size_t)row * HDIM + nt * 16 + quad * 4) = v;
                }
            }
        }
        t = tn;
    }
}

// ---------------------------------------------------------------------------
// proj: persistent. Sections:
//  [0,S0B)          gd_top + gg_top in 64KB LDS -> A_gd(+b1_gd), A_gg(+b1_gg)
//  [S0B,S0B+S1B)    gg_bot -> B_gg
//  [S0B+S1B,+S2B)   gd_bot -> B_gd (disease z)
// z_gene read 2x total (was 3x), one barrier per block lifetime.
// ---------------------------------------------------------------------------
__global__ __launch_bounds__(256) void proj_kernel(
    const void* __restrict__ Zg, const void* __restrict__ Zd,
    const uint4* __restrict__ img, const float* __restrict__ params,
    unsigned short* __restrict__ A_gd, unsigned short* __restrict__ B_gd,
    unsigned short* __restrict__ A_gg, unsigned short* __restrict__ B_gg,
    int NG, int ND, const int* __restrict__ flagp)
{
    __shared__ uint4 sW[4096];  // 64 KB
    int id = blockIdx.x;
    int tid  = threadIdx.x;
    int lane = tid & 63;
    int wave = tid >> 6;
    int nl   = lane & 15;
    int quad = lane >> 4;

    int sec, lblk, nb;
    if (id < S0B)            { sec = 0; lblk = id;             nb = S0B; }
    else if (id < S0B + S1B) { sec = 1; lblk = id - S0B;       nb = S1B; }
    else                     { sec = 2; lblk = id - S0B - S1B; nb = S2B; }

    if (sec == 0) {
#pragma unroll
        for (int i = 0; i < 8; ++i) sW[tid + i * 256] = img[tid + i * 256];              // gd_top
#pragma unroll
        for (int i = 0; i < 8; ++i) sW[2048 + tid + i * 256] = img[4096 + tid + i * 256]; // gg_top
    } else if (sec == 1) {
#pragma unroll
        for (int i = 0; i < 8; ++i) sW[tid + i * 256] = img[6144 + tid + i * 256];        // gg_bot
    } else {
#pragma unroll
        for (int i = 0; i < 8; ++i) sW[tid + i * 256] = img[2048 + tid + i * 256];        // gd_bot
    }
    __syncthreads();

    int flag = *flagp;
    if (sec == 0) {
        int nt64 = (NG + 63) >> 6;
        if (flag) proj_loop<true , 2>(Zg, A_gd, A_gg, params, params + 256, sW, NG, nt64, lblk, nb, wave, nl, quad);
        else      proj_loop<false, 2>(Zg, A_gd, A_gg, params, params + 256, sW, NG, nt64, lblk, nb, wave, nl, quad);
    } else if (sec == 1) {
        int nt64 = (NG + 63) >> 6;
        if (flag) proj_loop<true , 1>(Zg, B_gg, nullptr, params + 768, nullptr, sW, NG, nt64, lblk, nb, wave, nl, quad);
        else      proj_loop<false, 1>(Zg, B_gg, nullptr, params + 768, nullptr, sW, NG, nt64, lblk, nb, wave, nl, quad);
    } else {
        int nt64 = (ND + 63) >> 6;
        if (flag) proj_loop<true , 1>(Zd, B_gd, nullptr, params + 768, nullptr, sW, ND, nt64, lblk, nb, wave, nl, quad);
        else      proj_loop<false, 1>(Zd, B_gd, nullptr, params + 768, nullptr, sW, ND, nt64, lblk, nb, wave, nl, quad);
    }
}

// ---------------------------------------------------------------------------
// edge (R5's measured-best shape): 8 lanes/edge, 2 edges per lane-group
// (8 outstanding 16B data loads/lane). out[e] = relu(A[src]+B[dst]).w2 + b2
// (b1 pre-folded into A). rel block-uniform -> w2/b2 scalar; idx as one
// int2 pair per 2 edges. Clamped loads, guarded stores.
// ---------------------------------------------------------------------------
__global__ __launch_bounds__(256) void edge_kernel(
    const int* __restrict__ edges_gd, const int* __restrict__ edges_gg,
    const unsigned short* __restrict__ A_gd, const unsigned short* __restrict__ B_gd,
    const unsigned short* __restrict__ A_gg, const unsigned short* __restrict__ B_gg,
    const float* __restrict__ params,
    void* __restrict__ out, int E, int nb, const int* __restrict__ flagp)
{
    int rel = ((int)blockIdx.x >= nb) ? 1 : 0;
    int blk = blockIdx.x - rel * nb;
    const int* edges = rel ? edges_gg : edges_gd;
    const unsigned short* A = rel ? A_gg : A_gd;
    const unsigned short* B = rel ? B_gg : B_gd;
    const float* w2 = params + 128 + rel * 256;   // block-uniform
    float b2 = params[512 + rel];

    int tid  = threadIdx.x;
    int lane = tid & 63;
    int wave = tid >> 6;
    int nl   = lane & 7;    // lane within edge-group
    int grp  = lane >> 3;   // 8 groups per wave

    float w2f[16];
#pragma unroll
    for (int i = 0; i < 4; ++i) {
        float4 t = *(const float4*)(w2 + nl * 16 + i * 4);
        w2f[i * 4 + 0] = t.x; w2f[i * 4 + 1] = t.y;
        w2f[i * 4 + 2] = t.z; w2f[i * 4 + 3] = t.w;
    }

    int e0 = blk * 64 + (wave * 8 + grp) * 2;
    int e1 = e0 + 1;
    int emax = E - 2 > 0 ? E - 2 : 0;
    int ec = e0 < emax ? e0 : emax;
    int sel = e0 - ec;
    int2 sp = *(const int2*)(edges + ec);
    int2 dp = *(const int2*)(edges + E + ec);
    int src0 = sel ? sp.y : sp.x;
    int dst0 = sel ? dp.y : dp.x;
    int src1 = sp.y;
    int dst1 = dp.y;

    const uint4* a0p = (const uint4*)(A + (size_t)src0 * HDIM) + nl * 2;
    const uint4* b0p = (const uint4*)(B + (size_t)dst0 * HDIM) + nl * 2;
    const uint4* a1p = (const uint4*)(A + (size_t)src1 * HDIM) + nl * 2;
    const uint4* b1p = (const uint4*)(B + (size_t)dst1 * HDIM) + nl * 2;
    uint4 a0[2] = {a0p[0], a0p[1]};
    uint4 c0[2] = {b0p[0], b0p[1]};
    uint4 a1[2] = {a1p[0], a1p[1]};
    uint4 c1[2] = {b1p[0], b1p[1]};

    float acc0 = 0.f, acc1 = 0.f;
#pragma unroll
    for (int i = 0; i < 2; ++i) {
        const unsigned* au0 = (const unsigned*)&a0[i];
        const unsigned* cu0 = (const unsigned*)&c0[i];
        const unsigned* au1 = (const unsigned*)&a1[i];
        const unsigned* cu1 = (const unsigned*)&c1[i];
#pragma unroll
        for (int j = 0; j < 4; ++j) {
            int ch = i * 8 + j * 2;
            float x0 = __uint_as_float(au0[j] << 16);
            float x1 = __uint_as_float(au0[j] & 0xffff0000u);
            float y0 = __uint_as_float(cu0[j] << 16);
            float y1 = __uint_as_float(cu0[j] & 0xffff0000u);
            acc0 = fmaf(fmaxf(x0 + y0, 0.f), w2f[ch], acc0);
            acc0 = fmaf(fmaxf(x1 + y1, 0.f), w2f[ch + 1], acc0);
            float u0 = __uint_as_float(au1[j] << 16);
            float u1 = __uint_as_float(au1[j] & 0xffff0000u);
            float v0 = __uint_as_float(cu1[j] << 16);
            float v1 = __uint_as_float(cu1[j] & 0xffff0000u);
            acc1 = fmaf(fmaxf(u0 + v0, 0.f), w2f[ch], acc1);
            acc1 = fmaf(fmaxf(u1 + v1, 0.f), w2f[ch + 1], acc1);
        }
    }
    acc0 += __shfl_xor(acc0, 1); acc1 += __shfl_xor(acc1, 1);
    acc0 += __shfl_xor(acc0, 2); acc1 += __shfl_xor(acc1, 2);
    acc0 += __shfl_xor(acc0, 4); acc1 += __shfl_xor(acc1, 4);

    if (nl == 0) {
        int flag = *flagp;
        size_t base = (size_t)rel * E;
        if (e0 < E) {
            float r = acc0 + b2;
            if (flag) ((unsigned short*)out)[base + e0] = f2b(r);
            else      ((float*)out)[base + e0] = r;
        }
        if (e1 < E) {
            float r = acc1 + b2;
            if (flag) ((unsigned short*)out)[base + e1] = f2b(r);
            else      ((float*)out)[base + e1] = r;
        }
    }
}

// ---------------------------------------------------------------------------
// Fallback path (ws too small): detect + full per-edge MLP, one edge/block.
// ---------------------------------------------------------------------------
__global__ __launch_bounds__(256) void detect_kernel(
    const unsigned short* __restrict__ zbits, int* __restrict__ flag)
{
    int f = local_detect(zbits);
    if (threadIdx.x == 0) *flag = f;
}

__global__ __launch_bounds__(128) void naive_edge_kernel(
    const int* __restrict__ edges,
    const void* __restrict__ zsrc, const void* __restrict__ zdst,
    const void* __restrict__ w1, const void* __restrict__ b1,
    const void* __restrict__ w2, const void* __restrict__ b2,
    void* __restrict__ out, size_t eoff, int E,
    const int* __restrict__ flagp)
{
    int flag = flagp ? *flagp : 0;
    __shared__ float zs[128], zd[128], red[128];
    int e = blockIdx.x;
    int n = threadIdx.x;
    int src = edges[e], dst = edges[E + e];
    zs[n] = ldv(zsrc, (size_t)src * HDIM + n, flag);
    zd[n] = ldv(zdst, (size_t)dst * HDIM + n, flag);
    __syncthreads();
    float acc = ldv(b1, n, flag);
    for (int k = 0; k < 128; ++k) acc = fmaf(zs[k], ldv(w1, (size_t)k * HDIM + n, flag), acc);
    for (int k = 0; k < 128; ++k) acc = fmaf(zd[k], ldv(w1, (size_t)(128 + k) * HDIM + n, flag), acc);
    red[n] = fmaxf(acc, 0.f) * ldv(w2, n, flag);
    __syncthreads();
    for (int s = 64; s > 0; s >>= 1) {
        if (n < s) red[n] += red[n + s];
        __syncthreads();
    }
    if (n == 0) {
        float r = red[0] + ldv(b2, 0, flag);
        if (flag) ((unsigned short*)out)[eoff + e] = f2b(r);
        else      ((float*)out)[eoff + e] = r;
    }
}

extern "C" void kernel_launch(void* const* d_in, const int* in_sizes, int n_in,
                              void* d_out, int out_size, void* d_ws, size_t ws_size,
                              hipStream_t stream)
{
    const void* z_gene = d_in[0];
    const void* z_dis  = d_in[1];
    const int* edges_gd = (const int*)d_in[2];
    const int* edges_gg = (const int*)d_in[3];
    const void* w1_gd = d_in[4];
    const void* b1_gd = d_in[5];
    const void* w2_gd = d_in[6];
    const void* b2_gd = d_in[7];
    const void* w1_gg = d_in[8];
    const void* b1_gg = d_in[9];
    const void* w2_gg = d_in[10];
    const void* b2_gg = d_in[11];

    int NG = in_sizes[0] / HDIM;   // 100000
    int ND = in_sizes[1] / HDIM;   // 20000
    int E  = in_sizes[2] / 2;      // 500000

    // workspace layout (bytes)
    size_t off_flag   = 0;
    size_t off_params = 256;
    size_t off_img    = 256 + 4096;                     // params: 896 f32 padded
    size_t off_Agd    = off_img + 131072;
    size_t off_Bgd    = off_Agd + (size_t)NG * HDIM * 2;
    size_t off_Agg    = off_Bgd + (size_t)ND * HDIM * 2;
    size_t off_Bgg    = off_Agg + (size_t)NG * HDIM * 2;
    size_t need       = off_Bgg + (size_t)NG * HDIM * 2;

    char* ws = (char*)d_ws;

    if (ws_size < need) {
        const int* flagp = nullptr;
        if (ws_size >= 16) {
            detect_kernel<<<1, 256, 0, stream>>>((const unsigned short*)z_gene, (int*)ws);
            flagp = (const int*)ws;
        }
        naive_edge_kernel<<<E, 128, 0, stream>>>(edges_gd, z_gene, z_dis,
                                                 w1_gd, b1_gd, w2_gd, b2_gd,
                                                 d_out, 0, E, flagp);
        naive_edge_kernel<<<E, 128, 0, stream>>>(edges_gg, z_gene, z_gene,
                                                 w1_gg, b1_gg, w2_gg, b2_gg,
                                                 d_out, (size_t)E, E, flagp);
        return;
    }

    int* flag = (int*)(ws + off_flag);
    float* params = (float*)(ws + off_params);
    unsigned short* img = (unsigned short*)(ws + off_img);
    unsigned short* Agd = (unsigned short*)(ws + off_Agd);
    unsigned short* Bgd = (unsigned short*)(ws + off_Bgd);
    unsigned short* Agg = (unsigned short*)(ws + off_Agg);
    unsigned short* Bgg = (unsigned short*)(ws + off_Bgg);

    prep_kernel<<<33, 256, 0, stream>>>((const unsigned short*)z_gene,
                                        w1_gd, w1_gg, b1_gd, w2_gd, b2_gd,
                                        b1_gg, w2_gg, b2_gg, img, params, flag);

    const uint4* img4 = (const uint4*)img;
    proj_kernel<<<S0B + S1B + S2B, 256, 0, stream>>>(z_gene, z_dis, img4, params,
                                                     Agd, Bgd, Agg, Bgg,
                                                     NG, ND, flag);

    int nb = (E + 63) / 64;
    edge_kernel<<<2 * nb, 256, 0, stream>>>(edges_gd, edges_gg, Agd, Bgd, Agg, Bgg,
                                            params, d_out, E, nb, flag);
}